// Round 2
// baseline (3682.267 us; speedup 1.0000x reference)
//
#include <hip/hip_runtime.h>
#include <math.h>

// ---------------------------------------------------------------------------
// CapsuleNet forward, fp32 baseline.
// Pipeline:
//  1. wt_transpose: prim_w (256co,256ci,9,9) -> Wt[(p*256+ci)][co]  (p=ky*9+kx)
//  2. conv0: x(512,1,28,28) -> relu -> y0 NHWC (512,20,20,256)
//  3. prim_gemm: implicit-im2col GEMM  M=18432 (b,oy,ox)  N=256(co)  K=20736
//     -> y1 in NCHW-flat layout [(b*256+co)*36 + oy*6+ox]  (+bias, no relu)
//  4. xhat: squash 8-elem capsules of y1 flat, dot with digit_w -> xhat(b,o,i)
//  5. routing: 3 dynamic-routing iterations per b, out[b,o] = |v_o|
// ---------------------------------------------------------------------------

// ---- 1. weight transpose: Wt[(p*256+ci)*256 + co] = W[co*20736 + ci*81 + p]
__global__ __launch_bounds__(256) void wt_transpose_kernel(
    const float* __restrict__ w, float* __restrict__ wt) {
  const int p   = blockIdx.x % 81;          // p inner so nearby blocks share lines
  const int ci0 = (blockIdx.x / 81) * 64;
  const int t   = threadIdx.x;              // co
  #pragma unroll 4
  for (int rep = 0; rep < 64; ++rep) {
    const int ci = ci0 + rep;
    wt[(size_t)(p * 256 + ci) * 256 + t] = w[(size_t)t * 20736 + ci * 81 + p];
  }
}

// ---- 2. conv0 stem: one block per image, thread t = output channel
__global__ __launch_bounds__(256) void conv0_kernel(
    const float* __restrict__ x, const float* __restrict__ w,
    const float* __restrict__ bias, float* __restrict__ y0) {
  __shared__ float wl[256 * 81];
  __shared__ float xl[784];
  const int t   = threadIdx.x;
  const int img = blockIdx.x;
  for (int j = t; j < 256 * 81; j += 256) wl[j] = w[j];
  for (int j = t; j < 784; j += 256) xl[j] = x[img * 784 + j];
  __syncthreads();
  const float bv = bias[t];
  float* yo = y0 + (size_t)img * 400 * 256 + t;
  for (int oy = 0; oy < 20; ++oy) {
    float acc[20];
    #pragma unroll
    for (int ox = 0; ox < 20; ++ox) acc[ox] = bv;
    for (int ky = 0; ky < 9; ++ky) {
      float xr[28];
      #pragma unroll
      for (int j = 0; j < 28; ++j) xr[j] = xl[(oy + ky) * 28 + j];
      #pragma unroll
      for (int kx = 0; kx < 9; ++kx) {
        const float wv = wl[t * 81 + ky * 9 + kx];
        #pragma unroll
        for (int ox = 0; ox < 20; ++ox)
          acc[ox] = fmaf(wv, xr[ox + kx], acc[ox]);
      }
    }
    #pragma unroll
    for (int ox = 0; ox < 20; ++ox) {
      const float v = acc[ox] > 0.f ? acc[ox] : 0.f;
      yo[(size_t)(oy * 20 + ox) * 256] = v;   // NHWC: coalesced across threads
    }
  }
}

// ---- 3. prim caps conv as implicit GEMM.
// Tile: BM=64, BN=128, BK=64.  Block = 256 threads, micro-tile 4x8.
// grid.x = 288 M-tiles * 2 N-tiles = 576 blocks.
__global__ __launch_bounds__(256, 3) void prim_gemm_kernel(
    const float* __restrict__ y0, const float* __restrict__ wt,
    const float* __restrict__ bias, float* __restrict__ y1) {
  __shared__ __align__(16) float As[64 * 64];    // [k][m]
  __shared__ __align__(16) float Bs[64 * 128];   // [k][co]
  const int t  = threadIdx.x;
  const int mt = blockIdx.x >> 1;
  const int nt = blockIdx.x & 1;

  // A-loader mapping: lane -> row, wave -> k quarter
  const int lr = t & 63, kq = t >> 6;
  const int r    = mt * 64 + lr;
  const int bimg = r / 36;
  const int s    = r - bimg * 36;
  const int oy   = s / 6;
  const int ox   = s - oy * 6;
  const float* abase = y0 + ((size_t)(bimg * 20 + 2 * oy) * 20 + 2 * ox) * 256;

  const int cob = nt * 128;
  const int tx = t & 15, ty = t >> 4;

  float acc[4][8];
  #pragma unroll
  for (int m = 0; m < 4; ++m)
    #pragma unroll
    for (int n = 0; n < 8; ++n) acc[m][n] = 0.f;

  for (int kk = 0; kk < 324; ++kk) {
    const int seg = kk >> 2;            // ky*9+kx
    const int ci0 = (kk & 3) << 6;      // 0,64,128,192
    const int ky  = seg / 9;
    const int kx  = seg - ky * 9;
    const float* ap = abase + (ky * 20 + kx) * 256 + ci0;
    const float* bp = wt + (size_t)(seg * 256 + ci0) * 256 + cob;

    __syncthreads();   // previous tile's compute done before overwrite
    // stage A transposed: 4 float4 loads/thread, stride-1 LDS writes
    #pragma unroll
    for (int j = 0; j < 4; ++j) {
      const int kof = kq * 4 + j * 16;
      const float4 v = *(const float4*)(ap + kof);
      As[(kof + 0) * 64 + lr] = v.x;
      As[(kof + 1) * 64 + lr] = v.y;
      As[(kof + 2) * 64 + lr] = v.z;
      As[(kof + 3) * 64 + lr] = v.w;
    }
    // stage B: 8 float4 loads/thread, fully coalesced
    #pragma unroll
    for (int i = 0; i < 8; ++i) {
      const int f   = t + i * 256;
      const int kb  = f >> 5;
      const int co4 = (f & 31) << 2;
      *(float4*)&Bs[kb * 128 + co4] = *(const float4*)(bp + (size_t)kb * 256 + co4);
    }
    __syncthreads();

    #pragma unroll 8
    for (int k = 0; k < 64; ++k) {
      const float4 a  = *(const float4*)&As[k * 64 + ty * 4];
      const float4 b0 = *(const float4*)&Bs[k * 128 + tx * 4];
      const float4 b1 = *(const float4*)&Bs[k * 128 + 64 + tx * 4];
      const float av[4] = {a.x, a.y, a.z, a.w};
      const float bv[8] = {b0.x, b0.y, b0.z, b0.w, b1.x, b1.y, b1.z, b1.w};
      #pragma unroll
      for (int m = 0; m < 4; ++m)
        #pragma unroll
        for (int n = 0; n < 8; ++n)
          acc[m][n] = fmaf(av[m], bv[n], acc[m][n]);
    }
  }

  // epilogue: y1[(b*256+co)*36 + s] = acc + bias[co]
  #pragma unroll
  for (int m = 0; m < 4; ++m) {
    const int rr = mt * 64 + ty * 4 + m;
    const int bq = rr / 36;
    const int ss = rr - bq * 36;
    float* orow = y1 + (size_t)bq * 9216 + ss;
    #pragma unroll
    for (int n = 0; n < 8; ++n) {
      const int co = cob + ((n & 4) << 4) + tx * 4 + (n & 3);
      orow[(size_t)co * 36] = acc[m][n] + bias[co];
    }
  }
}

// ---- 4. capsule squash + x_hat einsum: thread per (b,i)
__global__ __launch_bounds__(256) void xhat_kernel(
    const float* __restrict__ y1, const float* __restrict__ dw,
    float* __restrict__ xhat) {
  const int gid = blockIdx.x * 256 + threadIdx.x;   // 0..589823
  const int b = gid / 1152;
  const int i = gid - b * 1152;
  const float4 p0 = *(const float4*)(y1 + (size_t)b * 9216 + i * 8);
  const float4 p1 = *(const float4*)(y1 + (size_t)b * 9216 + i * 8 + 4);
  const float n2 = p0.x * p0.x + p0.y * p0.y + p0.z * p0.z + p0.w * p0.w +
                   p1.x * p1.x + p1.y * p1.y + p1.z * p1.z + p1.w * p1.w;
  const float nn = sqrtf(n2);
  const float sc = n2 / (1.f + n2) / (nn + 1e-8f);
  float u[8];
  u[0] = p0.x * sc; u[1] = p0.y * sc; u[2] = p0.z * sc; u[3] = p0.w * sc;
  u[4] = p1.x * sc; u[5] = p1.y * sc; u[6] = p1.z * sc; u[7] = p1.w * sc;
  #pragma unroll
  for (int o = 0; o < 10; ++o) {
    const float4 w0 = *(const float4*)(dw + (size_t)(o * 1152 + i) * 8);
    const float4 w1 = *(const float4*)(dw + (size_t)(o * 1152 + i) * 8 + 4);
    float d = w0.x * u[0];
    d = fmaf(w0.y, u[1], d);
    d = fmaf(w0.z, u[2], d);
    d = fmaf(w0.w, u[3], d);
    d = fmaf(w1.x, u[4], d);
    d = fmaf(w1.y, u[5], d);
    d = fmaf(w1.z, u[6], d);
    d = fmaf(w1.w, u[7], d);
    xhat[(size_t)(b * 10 + o) * 1152 + i] = d;
  }
}

// ---- 5. dynamic routing: one block per batch image
__global__ __launch_bounds__(256) void routing_kernel(
    const float* __restrict__ xhat, float* __restrict__ out) {
  __shared__ float xh[11520];   // [o][i]
  __shared__ float bl[11520];   // b_logits
  __shared__ float red[48];     // [o][wave]
  __shared__ float vbc[10];
  const int t = threadIdx.x;
  const int b = blockIdx.x;
  for (int j = t; j < 11520; j += 256) {
    xh[j] = xhat[(size_t)b * 11520 + j];
    bl[j] = 0.f;
  }
  __syncthreads();
  const int lane = t & 63, wv = t >> 6;
  float vout[10];
  for (int it = 0; it < 3; ++it) {
    float sp[10];
    #pragma unroll
    for (int o = 0; o < 10; ++o) sp[o] = 0.f;
    for (int i = t; i < 1152; i += 256) {
      float e[10];
      float mx = bl[i];
      #pragma unroll
      for (int o = 1; o < 10; ++o) mx = fmaxf(mx, bl[o * 1152 + i]);
      float se = 0.f;
      #pragma unroll
      for (int o = 0; o < 10; ++o) { e[o] = expf(bl[o * 1152 + i] - mx); se += e[o]; }
      const float inv = 1.f / se;
      #pragma unroll
      for (int o = 0; o < 10; ++o) sp[o] += e[o] * inv * xh[o * 1152 + i];
    }
    #pragma unroll
    for (int o = 0; o < 10; ++o) {
      float v = sp[o];
      #pragma unroll
      for (int d = 32; d > 0; d >>= 1) v += __shfl_xor(v, d, 64);
      if (lane == 0) red[o * 4 + wv] = v;
    }
    __syncthreads();
    if (t < 10) {
      const float s = red[t * 4] + red[t * 4 + 1] + red[t * 4 + 2] + red[t * 4 + 3];
      const float n = fabsf(s);
      const float sc = (n * n) / (1.f + n * n) / (n + 1e-8f);
      vbc[t] = sc * s;
    }
    __syncthreads();
    #pragma unroll
    for (int o = 0; o < 10; ++o) vout[o] = vbc[o];
    if (it < 2) {
      for (int i = t; i < 1152; i += 256) {
        #pragma unroll
        for (int o = 0; o < 10; ++o) bl[o * 1152 + i] += vout[o] * xh[o * 1152 + i];
      }
    }
    __syncthreads();
  }
  if (t < 10) out[b * 10 + t] = fabsf(vout[t]);
}

// ---------------------------------------------------------------------------
extern "C" void kernel_launch(void* const* d_in, const int* in_sizes, int n_in,
                              void* d_out, int out_size, void* d_ws, size_t ws_size,
                              hipStream_t stream) {
  const float* x   = (const float*)d_in[0];
  const float* c0w = (const float*)d_in[1];
  const float* c0b = (const float*)d_in[2];
  const float* pw  = (const float*)d_in[3];
  const float* pb  = (const float*)d_in[4];
  const float* dw  = (const float*)d_in[5];
  float* out = (float*)d_out;
  float* ws  = (float*)d_ws;

  float* y0 = ws;                            // 52,428,800 floats (NHWC stem out)
  float* wt = ws + 52428800;                 //  5,308,416 floats (transposed W)
  float* y1 = ws + 52428800 + 5308416;       //  4,718,592 floats (prim out, NCHW-flat)
  float* xh = ws;                            //  5,898,240 floats (reuses y0 region)

  hipLaunchKernelGGL(wt_transpose_kernel, dim3(324), dim3(256), 0, stream, pw, wt);
  hipLaunchKernelGGL(conv0_kernel, dim3(512), dim3(256), 0, stream, x, c0w, c0b, y0);
  hipLaunchKernelGGL(prim_gemm_kernel, dim3(576), dim3(256), 0, stream, y0, wt, pb, y1);
  hipLaunchKernelGGL(xhat_kernel, dim3(2304), dim3(256), 0, stream, y1, dw, xh);
  hipLaunchKernelGGL(routing_kernel, dim3(512), dim3(256), 0, stream, xh, out);
}

// Round 5
// 1980.088 us; speedup vs baseline: 1.8596x; 1.8596x over previous
//
#include <hip/hip_runtime.h>
#include <math.h>

// ---------------------------------------------------------------------------
// CapsuleNet forward. prim-caps conv = bf16 MFMA GEMM with 3-term hi/lo
// split precision (fp32-accurate): acc += Ah*Bh + Ah*Bl + Al*Bh.
//   M=18432 (b,oy,ox)  N=256 (co)  K=20736 (81 taps x 256 ci)
//   BM=128 BN=256 BK=64, 8 waves, wave-tile 64x64.
//   K-split 8 accumulated via unsafeAtomicAdd into one fp32 buffer (18.9 MB),
//   zero-initialized each launch. Total ws = 249.8 MB (= round-0 proven size).
// ---------------------------------------------------------------------------

typedef float f32x4 __attribute__((ext_vector_type(4)));
typedef short s16x8 __attribute__((ext_vector_type(8)));

__device__ __forceinline__ ushort f2bf(float f) {   // RNE f32 -> bf16 bits
  unsigned u = __float_as_uint(f);
  u += 0x7FFFu + ((u >> 16) & 1u);
  return (ushort)(u >> 16);
}
__device__ __forceinline__ float bf2f(ushort h) {
  return __uint_as_float(((unsigned)h) << 16);
}

// ---- 0. zero the partial-accumulator buffer (ws is poisoned every launch)
__global__ __launch_bounds__(256) void zero_part_kernel(float* __restrict__ p) {
  uint4 z = {0u, 0u, 0u, 0u};
  uint4* dst = (uint4*)p + (size_t)blockIdx.x * 1024 + threadIdx.x;
  #pragma unroll
  for (int i = 0; i < 4; ++i) dst[i * 256] = z;   // 1152 blk * 256 thr * 4 = 1,179,648 uint4
}

// ---- 1. weight split+transpose: Wt[co][p][ci] hi/lo <- w[co][ci][p]
__global__ __launch_bounds__(256) void wt_split_kernel(
    const float* __restrict__ w, ushort* __restrict__ wth,
    ushort* __restrict__ wtl) {
  const int co = blockIdx.x;
  const int t  = threadIdx.x;
  const float* src = w + (size_t)co * 20736;
  ushort* dh = wth + (size_t)co * 20736;
  ushort* dl = wtl + (size_t)co * 20736;
  for (int j = t; j < 20736; j += 256) {
    const float v = src[j];          // j = ci*81 + p
    const int ci = j / 81;
    const int p  = j - ci * 81;
    const ushort h = f2bf(v);
    const ushort l = f2bf(v - bf2f(h));
    dh[p * 256 + ci] = h;
    dl[p * 256 + ci] = l;
  }
}

// ---- 2. conv0 stem -> y0 NHWC as bf16 hi/lo
__global__ __launch_bounds__(256) void conv0_kernel(
    const float* __restrict__ x, const float* __restrict__ w,
    const float* __restrict__ bias, ushort* __restrict__ y0h,
    ushort* __restrict__ y0l) {
  __shared__ float wl[256 * 81];
  __shared__ float xl[784];
  const int t   = threadIdx.x;
  const int img = blockIdx.x;
  for (int j = t; j < 256 * 81; j += 256) wl[j] = w[j];
  for (int j = t; j < 784; j += 256) xl[j] = x[img * 784 + j];
  __syncthreads();
  const float bv = bias[t];
  ushort* yh = y0h + (size_t)img * 400 * 256 + t;
  ushort* yl = y0l + (size_t)img * 400 * 256 + t;
  for (int oy = 0; oy < 20; ++oy) {
    float acc[20];
    #pragma unroll
    for (int ox = 0; ox < 20; ++ox) acc[ox] = bv;
    for (int ky = 0; ky < 9; ++ky) {
      float xr[28];
      #pragma unroll
      for (int j = 0; j < 28; ++j) xr[j] = xl[(oy + ky) * 28 + j];
      #pragma unroll
      for (int kx = 0; kx < 9; ++kx) {
        const float wv = wl[t * 81 + ky * 9 + kx];
        #pragma unroll
        for (int ox = 0; ox < 20; ++ox)
          acc[ox] = fmaf(wv, xr[ox + kx], acc[ox]);
      }
    }
    #pragma unroll
    for (int ox = 0; ox < 20; ++ox) {
      const float v = acc[ox] > 0.f ? acc[ox] : 0.f;
      const ushort h = f2bf(v);
      const ushort l = f2bf(v - bf2f(h));
      yh[(size_t)(oy * 20 + ox) * 256] = h;
      yl[(size_t)(oy * 20 + ox) * 256] = l;
    }
  }
}

// ---- 3. MFMA GEMM, K-split 8. grid = ksp(8) x mt(144); 512 threads.
__global__ __launch_bounds__(512, 2) void prim_gemm_mfma(
    const ushort* __restrict__ y0h, const ushort* __restrict__ y0l,
    const ushort* __restrict__ wth, const ushort* __restrict__ wtl,
    float* __restrict__ part) {
  __shared__ ushort Ah[128 * 64], Al[128 * 64];   // [row][k] XOR-swizzled
  __shared__ ushort Bh[256 * 64], Bl[256 * 64];   // [co][k]  XOR-swizzled

  const int t   = threadIdx.x;
  const int bid = blockIdx.x;
  const int mt  = bid % 144;           // consecutive bids share ksp -> B in L2
  const int ksp = bid / 144;
  const int r0  = mt * 128;
  const int ks0   = ksp * 40 + (ksp < 4 ? ksp : 4);
  const int ksend = ks0 + (ksp < 4 ? 41 : 40);     // 324 chunks total

  // staging job precompute (fixed across K-chunks)
  int abase[2], aoff[2], bbase[4], boff[4];
  #pragma unroll
  for (int i = 0; i < 2; ++i) {
    const int j = t + i * 512;
    const int row = j >> 3, ch = j & 7;
    const int gr = r0 + row;
    const int img = gr / 36;
    const int s = gr - img * 36;
    const int oy = s / 6, ox = s - oy * 6;
    abase[i] = (img * 400 + oy * 40 + ox * 2) * 256 + ch * 8;
    aoff[i] = row * 128 + ((ch * 16) ^ ((row & 7) << 4));
  }
  #pragma unroll
  for (int i = 0; i < 4; ++i) {
    const int j = t + i * 512;
    const int row = j >> 3, ch = j & 7;
    bbase[i] = row * 20736 + ch * 8;
    boff[i] = row * 128 + ((ch * 16) ^ ((row & 7) << 4));
  }

  const int lane = t & 63;
  const int wid  = t >> 6;
  const int wm = wid >> 2, wn = wid & 3;           // 2 x 4 wave grid
  const int g = lane >> 4, lr = lane & 15;
  const int swz = (lr & 7) << 4;                   // in-row XOR mask (bits 4-6)

  f32x4 acc[4][4];
  #pragma unroll
  for (int mi = 0; mi < 4; ++mi)
    #pragma unroll
    for (int ni = 0; ni < 4; ++ni)
      acc[mi][ni] = (f32x4){0.f, 0.f, 0.f, 0.f};

  uint4 ra[2][2], rb[4][2];
  {  // prefetch first chunk
    const int pp = ks0 >> 2;
    const int py = pp / 9;
    const int poffA = (py * 20 + (pp - py * 9)) * 256 + ((ks0 & 3) << 6);
    const int poffB = ks0 << 6;
    #pragma unroll
    for (int i = 0; i < 2; ++i) {
      ra[i][0] = *(const uint4*)(y0h + abase[i] + poffA);
      ra[i][1] = *(const uint4*)(y0l + abase[i] + poffA);
    }
    #pragma unroll
    for (int i = 0; i < 4; ++i) {
      rb[i][0] = *(const uint4*)(wth + bbase[i] + poffB);
      rb[i][1] = *(const uint4*)(wtl + bbase[i] + poffB);
    }
  }

  for (int kk = ks0; kk < ksend; ++kk) {
    __syncthreads();                       // prev compute done, LDS reusable
    #pragma unroll
    for (int i = 0; i < 2; ++i) {
      *(uint4*)((char*)Ah + aoff[i]) = ra[i][0];
      *(uint4*)((char*)Al + aoff[i]) = ra[i][1];
    }
    #pragma unroll
    for (int i = 0; i < 4; ++i) {
      *(uint4*)((char*)Bh + boff[i]) = rb[i][0];
      *(uint4*)((char*)Bl + boff[i]) = rb[i][1];
    }
    __syncthreads();                       // tile visible
    if (kk + 1 < ksend) {                  // prefetch next under compute
      const int nk = kk + 1;
      const int pp = nk >> 2;
      const int py = pp / 9;
      const int poffA = (py * 20 + (pp - py * 9)) * 256 + ((nk & 3) << 6);
      const int poffB = nk << 6;
      #pragma unroll
      for (int i = 0; i < 2; ++i) {
        ra[i][0] = *(const uint4*)(y0h + abase[i] + poffA);
        ra[i][1] = *(const uint4*)(y0l + abase[i] + poffA);
      }
      #pragma unroll
      for (int i = 0; i < 4; ++i) {
        rb[i][0] = *(const uint4*)(wth + bbase[i] + poffB);
        rb[i][1] = *(const uint4*)(wtl + bbase[i] + poffB);
      }
    }
    #pragma unroll
    for (int ks = 0; ks < 2; ++ks) {
      s16x8 bhv[4], blv[4];
      #pragma unroll
      for (int ni = 0; ni < 4; ++ni) {
        const int off = (wn * 64 + ni * 16 + lr) * 128 + ((ks * 64 + g * 16) ^ swz);
        bhv[ni] = *(const s16x8*)((const char*)Bh + off);
        blv[ni] = *(const s16x8*)((const char*)Bl + off);
      }
      #pragma unroll
      for (int mi = 0; mi < 4; ++mi) {
        const int off = (wm * 64 + mi * 16 + lr) * 128 + ((ks * 64 + g * 16) ^ swz);
        const s16x8 ahv = *(const s16x8*)((const char*)Ah + off);
        const s16x8 alv = *(const s16x8*)((const char*)Al + off);
        #pragma unroll
        for (int ni = 0; ni < 4; ++ni) {
          acc[mi][ni] = __builtin_amdgcn_mfma_f32_16x16x32_bf16(ahv, bhv[ni], acc[mi][ni], 0, 0, 0);
          acc[mi][ni] = __builtin_amdgcn_mfma_f32_16x16x32_bf16(ahv, blv[ni], acc[mi][ni], 0, 0, 0);
          acc[mi][ni] = __builtin_amdgcn_mfma_f32_16x16x32_bf16(alv, bhv[ni], acc[mi][ni], 0, 0, 0);
        }
      }
    }
  }

  // epilogue: part[(b*256+co)*36 + s] += acc  (C/D: col=lane&15, row=g*4+q)
  #pragma unroll
  for (int mi = 0; mi < 4; ++mi) {
    #pragma unroll
    for (int q = 0; q < 4; ++q) {
      const int gr = r0 + wm * 64 + mi * 16 + g * 4 + q;
      const int img = gr / 36;
      const int s = gr - img * 36;
      float* prow = part + (size_t)img * 9216 + s;
      #pragma unroll
      for (int ni = 0; ni < 4; ++ni) {
        const int co = wn * 64 + ni * 16 + lr;
        unsafeAtomicAdd(&prow[co * 36], acc[mi][ni][q]);
      }
    }
  }
}

// ---- 4. bias + squash + x_hat einsum: thread per (b,i)
__global__ __launch_bounds__(256) void xhat_kernel(
    const float* __restrict__ part, const float* __restrict__ bias,
    const float* __restrict__ dw, float* __restrict__ xhat) {
  const int gid = blockIdx.x * 256 + threadIdx.x;
  const int b = gid / 1152;
  const int i = gid - b * 1152;
  const size_t base = (size_t)b * 9216 + i * 8;
  const f32x4 s0 = *(const f32x4*)(part + base);
  const f32x4 s1 = *(const f32x4*)(part + base + 4);
  float u[8];
  #pragma unroll
  for (int d = 0; d < 4; ++d) u[d] = s0[d] + bias[(i * 8 + d) / 36];
  #pragma unroll
  for (int d = 0; d < 4; ++d) u[4 + d] = s1[d] + bias[(i * 8 + 4 + d) / 36];
  float n2 = 0.f;
  #pragma unroll
  for (int d = 0; d < 8; ++d) n2 += u[d] * u[d];
  const float nn = sqrtf(n2);
  const float sc = n2 / (1.f + n2) / (nn + 1e-8f);
  #pragma unroll
  for (int d = 0; d < 8; ++d) u[d] *= sc;
  #pragma unroll
  for (int o = 0; o < 10; ++o) {
    const float4 w0 = *(const float4*)(dw + (size_t)(o * 1152 + i) * 8);
    const float4 w1 = *(const float4*)(dw + (size_t)(o * 1152 + i) * 8 + 4);
    float d = w0.x * u[0];
    d = fmaf(w0.y, u[1], d);
    d = fmaf(w0.z, u[2], d);
    d = fmaf(w0.w, u[3], d);
    d = fmaf(w1.x, u[4], d);
    d = fmaf(w1.y, u[5], d);
    d = fmaf(w1.z, u[6], d);
    d = fmaf(w1.w, u[7], d);
    xhat[(size_t)(b * 10 + o) * 1152 + i] = d;
  }
}

// ---- 5. dynamic routing: one block per batch image
__global__ __launch_bounds__(256) void routing_kernel(
    const float* __restrict__ xhat, float* __restrict__ out) {
  __shared__ float xh[11520];
  __shared__ float bl[11520];
  __shared__ float red[48];
  __shared__ float vbc[10];
  const int t = threadIdx.x;
  const int b = blockIdx.x;
  for (int j = t; j < 11520; j += 256) {
    xh[j] = xhat[(size_t)b * 11520 + j];
    bl[j] = 0.f;
  }
  __syncthreads();
  const int lane = t & 63, wv = t >> 6;
  float vout[10];
  for (int it = 0; it < 3; ++it) {
    float sp[10];
    #pragma unroll
    for (int o = 0; o < 10; ++o) sp[o] = 0.f;
    for (int i = t; i < 1152; i += 256) {
      float e[10];
      float mx = bl[i];
      #pragma unroll
      for (int o = 1; o < 10; ++o) mx = fmaxf(mx, bl[o * 1152 + i]);
      float se = 0.f;
      #pragma unroll
      for (int o = 0; o < 10; ++o) { e[o] = expf(bl[o * 1152 + i] - mx); se += e[o]; }
      const float inv = 1.f / se;
      #pragma unroll
      for (int o = 0; o < 10; ++o) sp[o] += e[o] * inv * xh[o * 1152 + i];
    }
    #pragma unroll
    for (int o = 0; o < 10; ++o) {
      float v = sp[o];
      #pragma unroll
      for (int d = 32; d > 0; d >>= 1) v += __shfl_xor(v, d, 64);
      if (lane == 0) red[o * 4 + wv] = v;
    }
    __syncthreads();
    if (t < 10) {
      const float s = red[t * 4] + red[t * 4 + 1] + red[t * 4 + 2] + red[t * 4 + 3];
      const float n = fabsf(s);
      const float sc = (n * n) / (1.f + n * n) / (n + 1e-8f);
      vbc[t] = sc * s;
    }
    __syncthreads();
    #pragma unroll
    for (int o = 0; o < 10; ++o) vout[o] = vbc[o];
    if (it < 2) {
      for (int i = t; i < 1152; i += 256) {
        #pragma unroll
        for (int o = 0; o < 10; ++o) bl[o * 1152 + i] += vout[o] * xh[o * 1152 + i];
      }
    }
    __syncthreads();
  }
  if (t < 10) out[b * 10 + t] = fabsf(vout[t]);
}

// ---------------------------------------------------------------------------
extern "C" void kernel_launch(void* const* d_in, const int* in_sizes, int n_in,
                              void* d_out, int out_size, void* d_ws, size_t ws_size,
                              hipStream_t stream) {
  const float* x   = (const float*)d_in[0];
  const float* c0w = (const float*)d_in[1];
  const float* c0b = (const float*)d_in[2];
  const float* pw  = (const float*)d_in[3];
  const float* pb  = (const float*)d_in[4];
  const float* dw  = (const float*)d_in[5];
  float* out = (float*)d_out;
  char* W = (char*)d_ws;

  // workspace layout (bytes), total 249,823,232 (== proven round-0 footprint):
  ushort* y0h  = (ushort*)(W);                    // 104,857,600
  ushort* y0l  = (ushort*)(W + 104857600);        // 104,857,600
  ushort* wth  = (ushort*)(W + 209715200);        //  10,616,832
  ushort* wtl  = (ushort*)(W + 220332032);        //  10,616,832
  float*  part = (float*)(W + 230948864);         //  18,874,368 (4,718,592 fp32)
  float*  xh   = (float*)(W);                     //  23,592,960 (over dead y0h)

  hipLaunchKernelGGL(wt_split_kernel, dim3(256), dim3(256), 0, stream, pw, wth, wtl);
  hipLaunchKernelGGL(conv0_kernel, dim3(512), dim3(256), 0, stream, x, c0w, c0b, y0h, y0l);
  hipLaunchKernelGGL(zero_part_kernel, dim3(1152), dim3(256), 0, stream, part);
  hipLaunchKernelGGL(prim_gemm_mfma, dim3(1152), dim3(512), 0, stream, y0h, y0l, wth, wtl, part);
  hipLaunchKernelGGL(xhat_kernel, dim3(2304), dim3(256), 0, stream, part, pb, dw, xh);
  hipLaunchKernelGGL(routing_kernel, dim3(512), dim3(256), 0, stream, xh, out);
}

// Round 7
// 1225.949 us; speedup vs baseline: 3.0036x; 1.6151x over previous
//
#include <hip/hip_runtime.h>
#include <math.h>

// ---------------------------------------------------------------------------
// CapsuleNet forward. prim-caps conv = bf16 MFMA GEMM, 3-term hi/lo split
// (acc += Ah*Bh + Ah*Bl + Al*Bh).  M=18432  N=256  K=20736.
// GEMM: BM=64 BN=256 BK=32, 256 thr (4 waves, wave-tile 64x64), LDS 40 KB,
// 3 blocks/CU, global_load_lds staging (swizzle pre-applied to global src),
// K-split 4 accumulated with unsafeAtomicAdd into one fp32 buffer.
// ---------------------------------------------------------------------------

typedef float f32x4 __attribute__((ext_vector_type(4)));
typedef short s16x8 __attribute__((ext_vector_type(8)));

#define GLD16(g, l)                                             \
  __builtin_amdgcn_global_load_lds(                             \
      (const __attribute__((address_space(1))) void*)(g),       \
      (__attribute__((address_space(3))) void*)(l), 16, 0, 0)

__device__ __forceinline__ ushort f2bf(float f) {   // RNE f32 -> bf16 bits
  unsigned u = __float_as_uint(f);
  u += 0x7FFFu + ((u >> 16) & 1u);
  return (ushort)(u >> 16);
}
__device__ __forceinline__ float bf2f(ushort h) {
  return __uint_as_float(((unsigned)h) << 16);
}

// ---- 0. zero the accumulator buffer (ws is poisoned every launch)
__global__ __launch_bounds__(256) void zero_part_kernel(float* __restrict__ p) {
  uint4 z = {0u, 0u, 0u, 0u};
  uint4* dst = (uint4*)p + (size_t)blockIdx.x * 1024 + threadIdx.x;
  #pragma unroll
  for (int i = 0; i < 4; ++i) dst[i * 256] = z;
}

// ---- 1. weight split+transpose via LDS: Wt[co][p][ci] hi/lo <- w[co][ci][p]
__global__ __launch_bounds__(256) void wt_split_kernel(
    const float* __restrict__ w, ushort* __restrict__ wth,
    ushort* __restrict__ wtl) {
  __shared__ float sb[20736];
  const int co = blockIdx.x;
  const int t  = threadIdx.x;
  const float* src = w + (size_t)co * 20736;
  for (int j = t; j < 20736; j += 256) sb[j] = src[j];   // coalesced
  __syncthreads();
  ushort* dh = wth + (size_t)co * 20736;
  ushort* dl = wtl + (size_t)co * 20736;
  for (int j = t; j < 20736; j += 256) {   // j = p*256 + ci  (coalesced writes)
    const int p  = j >> 8;
    const int ci = j & 255;
    const float v = sb[ci * 81 + p];       // stride-81: conflict-free (odd)
    const ushort h = f2bf(v);
    const ushort l = f2bf(v - bf2f(h));
    dh[j] = h;
    dl[j] = l;
  }
}

// ---- 2. conv0 stem -> y0 NHWC as bf16 hi/lo
__global__ __launch_bounds__(256) void conv0_kernel(
    const float* __restrict__ x, const float* __restrict__ w,
    const float* __restrict__ bias, ushort* __restrict__ y0h,
    ushort* __restrict__ y0l) {
  __shared__ float wl[256 * 81];
  __shared__ float xl[784];
  const int t   = threadIdx.x;
  const int img = blockIdx.x;
  for (int j = t; j < 256 * 81; j += 256) wl[j] = w[j];
  for (int j = t; j < 784; j += 256) xl[j] = x[img * 784 + j];
  __syncthreads();
  const float bv = bias[t];
  ushort* yh = y0h + (size_t)img * 400 * 256 + t;
  ushort* yl = y0l + (size_t)img * 400 * 256 + t;
  for (int oy = 0; oy < 20; ++oy) {
    float acc[20];
    #pragma unroll
    for (int ox = 0; ox < 20; ++ox) acc[ox] = bv;
    for (int ky = 0; ky < 9; ++ky) {
      float xr[28];
      #pragma unroll
      for (int j = 0; j < 28; ++j) xr[j] = xl[(oy + ky) * 28 + j];
      #pragma unroll
      for (int kx = 0; kx < 9; ++kx) {
        const float wv = wl[t * 81 + ky * 9 + kx];
        #pragma unroll
        for (int ox = 0; ox < 20; ++ox)
          acc[ox] = fmaf(wv, xr[ox + kx], acc[ox]);
      }
    }
    #pragma unroll
    for (int ox = 0; ox < 20; ++ox) {
      const float v = acc[ox] > 0.f ? acc[ox] : 0.f;
      const ushort h = f2bf(v);
      const ushort l = f2bf(v - bf2f(h));
      yh[(size_t)(oy * 20 + ox) * 256] = h;
      yl[(size_t)(oy * 20 + ox) * 256] = l;
    }
  }
}

// ---- 3. MFMA GEMM. grid = ksp(4) x mt(288), 256 threads (4 waves).
// LDS tiles: A[64][32], B[256][32] hi/lo, 64-B rows, slot-swizzle
// slot_phys = slot_log ^ ((row>>1)&3), folded into the global source addr.
__global__ __launch_bounds__(256, 3) void prim_gemm_mfma(
    const ushort* __restrict__ y0h, const ushort* __restrict__ y0l,
    const ushort* __restrict__ wth, const ushort* __restrict__ wtl,
    float* __restrict__ part) {
  __shared__ ushort Ah[64 * 32], Al[64 * 32];     //  4 KB each
  __shared__ ushort Bh[256 * 32], Bl[256 * 32];   // 16 KB each

  const int t   = threadIdx.x;
  const int bid = blockIdx.x;
  const int mt  = bid % 288;            // consecutive bids share ksp -> B in L2
  const int ksp = bid / 288;
  const int r0  = mt * 64;
  const int ks0 = ksp * 162, ksend = ks0 + 162;   // 648 BK-32 chunks total

  // A staging source: thread t -> row ar=t>>2, phys slot t&3 holds chunk ac
  const int ar = t >> 2;
  const int ac = (t & 3) ^ ((t >> 3) & 3);
  int asrc;
  {
    const int gr  = r0 + ar;
    const int img = gr / 36;
    const int s   = gr - img * 36;
    const int oy  = s / 6, ox = s - oy * 6;
    asrc = (img * 400 + oy * 40 + ox * 2) * 256 + ac * 8;
  }
  // B staging: job i covers rows [i*64, i*64+64)
  int bsrc[4];
  #pragma unroll
  for (int i = 0; i < 4; ++i) {
    const int j  = i * 256 + t;
    const int br = j >> 2;
    const int bc = (j & 3) ^ ((j >> 3) & 3);
    bsrc[i] = br * 20736 + bc * 8;
  }

  const int lane = t & 63, w = t >> 6;
  const int g = lane >> 4, lr = lane & 15;
  const int xg = ((g ^ ((lr >> 1) & 3)) << 4);    // frag-read in-row byte off

  f32x4 acc[4][4];
  #pragma unroll
  for (int mi = 0; mi < 4; ++mi)
    #pragma unroll
    for (int ni = 0; ni < 4; ++ni)
      acc[mi][ni] = (f32x4){0.f, 0.f, 0.f, 0.f};

  for (int kk = ks0; kk < ksend; ++kk) {
    const int seg = kk >> 3;             // ky*9+kx
    const int ci0 = (kk & 7) << 5;       // 32-ci chunk
    const int ky  = seg / 9, kx = seg - ky * 9;
    const int ao  = (ky * 20 + kx) * 256 + ci0;
    const int bo  = seg * 256 + ci0;

    __syncthreads();                     // prev tile's reads done
    GLD16(y0h + asrc + ao, (char*)Ah + w * 1024);
    GLD16(y0l + asrc + ao, (char*)Al + w * 1024);
    #pragma unroll
    for (int i = 0; i < 4; ++i) {
      GLD16(wth + bsrc[i] + bo, (char*)Bh + i * 4096 + w * 1024);
      GLD16(wtl + bsrc[i] + bo, (char*)Bl + i * 4096 + w * 1024);
    }
    __syncthreads();                     // implicit vmcnt(0) drain + barrier

    s16x8 bhv[4], blv[4];
    #pragma unroll
    for (int ni = 0; ni < 4; ++ni) {
      const int off = (w * 64 + ni * 16 + lr) * 64 + xg;
      bhv[ni] = *(const s16x8*)((const char*)Bh + off);
      blv[ni] = *(const s16x8*)((const char*)Bl + off);
    }
    #pragma unroll
    for (int mi = 0; mi < 4; ++mi) {
      const int off = (mi * 16 + lr) * 64 + xg;
      const s16x8 ahv = *(const s16x8*)((const char*)Ah + off);
      const s16x8 alv = *(const s16x8*)((const char*)Al + off);
      #pragma unroll
      for (int ni = 0; ni < 4; ++ni) {
        acc[mi][ni] = __builtin_amdgcn_mfma_f32_16x16x32_bf16(ahv, bhv[ni], acc[mi][ni], 0, 0, 0);
        acc[mi][ni] = __builtin_amdgcn_mfma_f32_16x16x32_bf16(ahv, blv[ni], acc[mi][ni], 0, 0, 0);
        acc[mi][ni] = __builtin_amdgcn_mfma_f32_16x16x32_bf16(alv, bhv[ni], acc[mi][ni], 0, 0, 0);
      }
    }
  }

  // epilogue: part[(img*256+co)*36 + s] += acc  (C/D: col=lane&15, row=g*4+q)
  #pragma unroll
  for (int mi = 0; mi < 4; ++mi) {
    #pragma unroll
    for (int q = 0; q < 4; ++q) {
      const int gr  = r0 + mi * 16 + g * 4 + q;
      const int img = gr / 36;
      const int s   = gr - img * 36;
      float* prow = part + (size_t)img * 9216 + s;
      #pragma unroll
      for (int ni = 0; ni < 4; ++ni) {
        const int co = w * 64 + ni * 16 + lr;
        unsafeAtomicAdd(&prow[co * 36], acc[mi][ni][q]);
      }
    }
  }
}

// ---- 4. bias + squash + x_hat einsum: thread per (b,i)
__global__ __launch_bounds__(256) void xhat_kernel(
    const float* __restrict__ part, const float* __restrict__ bias,
    const float* __restrict__ dw, float* __restrict__ xhat) {
  const int gid = blockIdx.x * 256 + threadIdx.x;
  const int b = gid / 1152;
  const int i = gid - b * 1152;
  const size_t base = (size_t)b * 9216 + i * 8;
  const f32x4 s0 = *(const f32x4*)(part + base);
  const f32x4 s1 = *(const f32x4*)(part + base + 4);
  float u[8];
  #pragma unroll
  for (int d = 0; d < 4; ++d) u[d] = s0[d] + bias[(i * 8 + d) / 36];
  #pragma unroll
  for (int d = 0; d < 4; ++d) u[4 + d] = s1[d] + bias[(i * 8 + 4 + d) / 36];
  float n2 = 0.f;
  #pragma unroll
  for (int d = 0; d < 8; ++d) n2 += u[d] * u[d];
  const float nn = sqrtf(n2);
  const float sc = n2 / (1.f + n2) / (nn + 1e-8f);
  #pragma unroll
  for (int d = 0; d < 8; ++d) u[d] *= sc;
  #pragma unroll
  for (int o = 0; o < 10; ++o) {
    const float4 w0 = *(const float4*)(dw + (size_t)(o * 1152 + i) * 8);
    const float4 w1 = *(const float4*)(dw + (size_t)(o * 1152 + i) * 8 + 4);
    float d = w0.x * u[0];
    d = fmaf(w0.y, u[1], d);
    d = fmaf(w0.z, u[2], d);
    d = fmaf(w0.w, u[3], d);
    d = fmaf(w1.x, u[4], d);
    d = fmaf(w1.y, u[5], d);
    d = fmaf(w1.z, u[6], d);
    d = fmaf(w1.w, u[7], d);
    xhat[(size_t)(b * 10 + o) * 1152 + i] = d;
  }
}

// ---- 5. dynamic routing: one block per batch image
__global__ __launch_bounds__(256) void routing_kernel(
    const float* __restrict__ xhat, float* __restrict__ out) {
  __shared__ float xh[11520];
  __shared__ float bl[11520];
  __shared__ float red[48];
  __shared__ float vbc[10];
  const int t = threadIdx.x;
  const int b = blockIdx.x;
  for (int j = t; j < 11520; j += 256) {
    xh[j] = xhat[(size_t)b * 11520 + j];
    bl[j] = 0.f;
  }
  __syncthreads();
  const int lane = t & 63, wv = t >> 6;
  float vout[10];
  for (int it = 0; it < 3; ++it) {
    float sp[10];
    #pragma unroll
    for (int o = 0; o < 10; ++o) sp[o] = 0.f;
    for (int i = t; i < 1152; i += 256) {
      float e[10];
      float mx = bl[i];
      #pragma unroll
      for (int o = 1; o < 10; ++o) mx = fmaxf(mx, bl[o * 1152 + i]);
      float se = 0.f;
      #pragma unroll
      for (int o = 0; o < 10; ++o) { e[o] = expf(bl[o * 1152 + i] - mx); se += e[o]; }
      const float inv = 1.f / se;
      #pragma unroll
      for (int o = 0; o < 10; ++o) sp[o] += e[o] * inv * xh[o * 1152 + i];
    }
    #pragma unroll
    for (int o = 0; o < 10; ++o) {
      float v = sp[o];
      #pragma unroll
      for (int d = 32; d > 0; d >>= 1) v += __shfl_xor(v, d, 64);
      if (lane == 0) red[o * 4 + wv] = v;
    }
    __syncthreads();
    if (t < 10) {
      const float s = red[t * 4] + red[t * 4 + 1] + red[t * 4 + 2] + red[t * 4 + 3];
      const float n = fabsf(s);
      const float sc = (n * n) / (1.f + n * n) / (n + 1e-8f);
      vbc[t] = sc * s;
    }
    __syncthreads();
    #pragma unroll
    for (int o = 0; o < 10; ++o) vout[o] = vbc[o];
    if (it < 2) {
      for (int i = t; i < 1152; i += 256) {
        #pragma unroll
        for (int o = 0; o < 10; ++o) bl[o * 1152 + i] += vout[o] * xh[o * 1152 + i];
      }
    }
    __syncthreads();
  }
  if (t < 10) out[b * 10 + t] = fabsf(vout[t]);
}

// ---------------------------------------------------------------------------
extern "C" void kernel_launch(void* const* d_in, const int* in_sizes, int n_in,
                              void* d_out, int out_size, void* d_ws, size_t ws_size,
                              hipStream_t stream) {
  const float* x   = (const float*)d_in[0];
  const float* c0w = (const float*)d_in[1];
  const float* c0b = (const float*)d_in[2];
  const float* pw  = (const float*)d_in[3];
  const float* pb  = (const float*)d_in[4];
  const float* dw  = (const float*)d_in[5];
  float* out = (float*)d_out;
  char* W = (char*)d_ws;

  // workspace layout (bytes), total 249,823,232:
  ushort* y0h  = (ushort*)(W);                    // 104,857,600
  ushort* y0l  = (ushort*)(W + 104857600);        // 104,857,600
  ushort* wth  = (ushort*)(W + 209715200);        //  10,616,832
  ushort* wtl  = (ushort*)(W + 220332032);        //  10,616,832
  float*  part = (float*)(W + 230948864);         //  18,874,368 (4,718,592 fp32)
  float*  xh   = (float*)(W);                     //  23,592,960 (over dead y0h)

  hipLaunchKernelGGL(wt_split_kernel, dim3(256), dim3(256), 0, stream, pw, wth, wtl);
  hipLaunchKernelGGL(conv0_kernel, dim3(512), dim3(256), 0, stream, x, c0w, c0b, y0h, y0l);
  hipLaunchKernelGGL(zero_part_kernel, dim3(1152), dim3(256), 0, stream, part);
  hipLaunchKernelGGL(prim_gemm_mfma, dim3(1152), dim3(256), 0, stream, y0h, y0l, wth, wtl, part);
  hipLaunchKernelGGL(xhat_kernel, dim3(2304), dim3(256), 0, stream, part, pb, dw, xh);
  hipLaunchKernelGGL(routing_kernel, dim3(512), dim3(256), 0, stream, xh, out);
}